// Round 1
// baseline (675.351 us; speedup 1.0000x reference)
//
#include <hip/hip_runtime.h>
#include <math.h>

#define LSEQ 16384
#define DMODEL 128
#define DINNER 256
#define DSTATE 16
#define DCONV 4
#define DTRANK 8
#define NLAYERS 2
#define ATTNDIM 64
#define NCLASSES 4
#define CHUNK 64
#define NCHUNK (LSEQ / CHUNK)      /* 256 */
#define NCH (DINNER * DSTATE)      /* 4096 */

// permuted position j -> original index perm[j]
// perm = concat([arange(i, L, rate) for i in range(rate)])
__device__ __forceinline__ int perm_of(int j, int rate) {
    int q = LSEQ / rate;
    int r = LSEQ - q * rate;
    int thresh = r * (q + 1);
    int i, k;
    if (j < thresh) { i = j / (q + 1); k = j - i * (q + 1); }
    else { int j2 = j - thresh; i = r + j2 / q; k = j2 - (i - r) * q; }
    return i + rate * k;
}

// C[M][ldc] = act(A[M][lda(cols 0..K)] @ W[N][K]^T + bias)
// MODE 0: plain store. MODE 1: C[perm(m)][n] += v (out_proj scatter + residual)
// ACT 0: none, 1: relu, 2: tanh
template<int BM, int BN, int BK, int TM, int TN, int ACT, int MODE>
__global__ __launch_bounds__(256) void gemm_tn(
    const float* __restrict__ A, int lda,
    const float* __restrict__ W,
    const float* __restrict__ bias,
    float* __restrict__ C, int ldc,
    int M, int N, int K, const int* __restrict__ ratep)
{
    constexpr int TX = BN / TN;
    constexpr int TY = BM / TM;
    static_assert(TX * TY == 256, "block must be 256 threads");
    constexpr int AV4 = (BM * BK) / (4 * 256);
    constexpr int WV4 = (BN * BK) / (4 * 256);
    __shared__ float sA[BK][BM + 4];
    __shared__ float sW[BK][BN + 4];
    const int tid = threadIdx.x;
    const int tx = tid % TX, ty = tid / TX;
    const int m0 = blockIdx.x * BM;
    const int n0 = blockIdx.y * BN;
    float acc[TM][TN];
#pragma unroll
    for (int i = 0; i < TM; i++)
#pragma unroll
        for (int j = 0; j < TN; j++) acc[i][j] = 0.f;

    for (int k0 = 0; k0 < K; k0 += BK) {
#pragma unroll
        for (int it = 0; it < AV4; it++) {
            int idx4 = it * 256 + tid;
            int e = idx4 * 4;
            int m = e / BK, kk = e % BK;
            float4 v = *reinterpret_cast<const float4*>(&A[(size_t)(m0 + m) * lda + k0 + kk]);
            sA[kk + 0][m] = v.x; sA[kk + 1][m] = v.y;
            sA[kk + 2][m] = v.z; sA[kk + 3][m] = v.w;
        }
#pragma unroll
        for (int it = 0; it < WV4; it++) {
            int idx4 = it * 256 + tid;
            int e = idx4 * 4;
            int n = e / BK, kk = e % BK;
            float4 v = make_float4(0.f, 0.f, 0.f, 0.f);
            if (n0 + n < N) v = *reinterpret_cast<const float4*>(&W[(size_t)(n0 + n) * K + k0 + kk]);
            sW[kk + 0][n] = v.x; sW[kk + 1][n] = v.y;
            sW[kk + 2][n] = v.z; sW[kk + 3][n] = v.w;
        }
        __syncthreads();
#pragma unroll
        for (int kk = 0; kk < BK; kk++) {
            float a[TM], w[TN];
#pragma unroll
            for (int i = 0; i < TM; i++) a[i] = sA[kk][ty * TM + i];
#pragma unroll
            for (int j = 0; j < TN; j++) w[j] = sW[kk][tx * TN + j];
#pragma unroll
            for (int i = 0; i < TM; i++)
#pragma unroll
                for (int j = 0; j < TN; j++) acc[i][j] = fmaf(a[i], w[j], acc[i][j]);
        }
        __syncthreads();
    }
    int rate = 0;
    if constexpr (MODE == 1) rate = *ratep;
#pragma unroll
    for (int i = 0; i < TM; i++) {
        int m = m0 + ty * TM + i;
        int orow = m;
        if constexpr (MODE == 1) orow = perm_of(m, rate);
#pragma unroll
        for (int j = 0; j < TN; j++) {
            int n = n0 + tx * TN + j;
            if (n < N) {
                float v = acc[i][j];
                if (bias) v += bias[n];
                if constexpr (ACT == 1) v = fmaxf(v, 0.f);
                if constexpr (ACT == 2) v = tanhf(v);
                if constexpr (MODE == 1) C[(size_t)orow * ldc + n] += v;
                else C[(size_t)orow * ldc + n] = v;
            }
        }
    }
}

// layernorm over 128; GATHER: row j reads source row perm(j)
template<bool GATHER>
__global__ __launch_bounds__(256) void ln_kernel(
    const float* __restrict__ h, const float* __restrict__ w, const float* __restrict__ b,
    float* __restrict__ out, const int* __restrict__ ratep)
{
    int lane = threadIdx.x & 63;
    int rowInBlk = threadIdx.x >> 6;
    int j = blockIdx.x * 4 + rowInBlk;
    int src = j;
    if (GATHER) src = perm_of(j, *ratep);
    float2 v = *reinterpret_cast<const float2*>(&h[(size_t)src * DMODEL + lane * 2]);
    float s = v.x + v.y;
    float s2 = v.x * v.x + v.y * v.y;
#pragma unroll
    for (int o = 1; o < 64; o <<= 1) {
        s += __shfl_xor(s, o);
        s2 += __shfl_xor(s2, o);
    }
    float mean = s * (1.f / DMODEL);
    float var = s2 * (1.f / DMODEL) - mean * mean;
    float inv = rsqrtf(var + 1e-5f);
    float2 wv = *reinterpret_cast<const float2*>(&w[lane * 2]);
    float2 bv = *reinterpret_cast<const float2*>(&b[lane * 2]);
    float2 o2;
    o2.x = (v.x - mean) * inv * wv.x + bv.x;
    o2.y = (v.y - mean) * inv * wv.y + bv.y;
    *reinterpret_cast<float2*>(&out[(size_t)j * DMODEL + lane * 2]) = o2;
}

// depthwise causal conv (k=4) over permuted sequence + silu. x = xz cols [0,256)
__global__ __launch_bounds__(256) void conv_silu_kernel(
    const float* __restrict__ xz, const float* __restrict__ cw, const float* __restrict__ cb,
    float* __restrict__ u)
{
    int idx = blockIdx.x * 256 + threadIdx.x;
    int d = idx & (DINNER - 1);
    int j = idx >> 8;
    float4 wv = *reinterpret_cast<const float4*>(&cw[d * 4]);
    const float* wp = reinterpret_cast<const float*>(&wv);
    float acc = cb[d];
#pragma unroll
    for (int k = 0; k < DCONV; k++) {
        int t = j - (DCONV - 1) + k;
        if (t >= 0) acc += xz[(size_t)t * 512 + d] * wp[k];
    }
    float sig = 1.f / (1.f + __expf(-acc));
    u[idx] = acc * sig;
}

// Chunked selective scan. One block per chunk (64 steps), one thread per d-channel.
// dbl rows (40 floats: dtr[8] | B[16] | C[16]) staged in LDS; dt recomputed in-reg.
// PHASEC=false: emit a_prod=exp(A*sum_dt) and h_local (zero init).
// PHASEC=true : init h from h_init, emit y = (sum_s h*C + u*D) * silu(z).
template<bool PHASEC>
__global__ __launch_bounds__(256) void scan_phase(
    const float* __restrict__ u, const float* __restrict__ dbl,
    const float* __restrict__ Wdt, const float* __restrict__ bdt,
    const float* __restrict__ A_log,
    const float* __restrict__ Dp, const float* __restrict__ xz,
    const float* __restrict__ h_init,
    float* __restrict__ a_prod, float* __restrict__ h_loc,
    float* __restrict__ yout)
{
    __shared__ float sRow[CHUNK][40];
    const int c = blockIdx.x;
    const int tid = threadIdx.x;
    for (int idx4 = tid; idx4 < CHUNK * 10; idx4 += 256) {
        int t = idx4 / 10;
        int c4 = idx4 % 10;
        float4 v = *reinterpret_cast<const float4*>(&dbl[(size_t)(c * CHUNK + t) * 40 + c4 * 4]);
        sRow[t][c4 * 4 + 0] = v.x; sRow[t][c4 * 4 + 1] = v.y;
        sRow[t][c4 * 4 + 2] = v.z; sRow[t][c4 * 4 + 3] = v.w;
    }
    __syncthreads();
    const int d = tid;
    float Areg[DSTATE];
#pragma unroll
    for (int s4 = 0; s4 < 4; s4++) {
        float4 v = *reinterpret_cast<const float4*>(&A_log[(size_t)d * DSTATE + s4 * 4]);
        Areg[s4 * 4 + 0] = -expf(v.x); Areg[s4 * 4 + 1] = -expf(v.y);
        Areg[s4 * 4 + 2] = -expf(v.z); Areg[s4 * 4 + 3] = -expf(v.w);
    }
    float4 w0 = *reinterpret_cast<const float4*>(&Wdt[(size_t)d * 8]);
    float4 w1 = *reinterpret_cast<const float4*>(&Wdt[(size_t)d * 8 + 4]);
    const float bdt_d = bdt[d];
    float h[DSTATE];
    if constexpr (PHASEC) {
        size_t base = (size_t)c * NCH + (size_t)d * DSTATE;
#pragma unroll
        for (int s4 = 0; s4 < 4; s4++) {
            float4 v = *reinterpret_cast<const float4*>(&h_init[base + s4 * 4]);
            h[s4 * 4 + 0] = v.x; h[s4 * 4 + 1] = v.y;
            h[s4 * 4 + 2] = v.z; h[s4 * 4 + 3] = v.w;
        }
    } else {
#pragma unroll
        for (int s = 0; s < DSTATE; s++) h[s] = 0.f;
    }
    float Dd = 0.f;
    if constexpr (PHASEC) Dd = Dp[d];
    float sumdt = 0.f;
    for (int t = 0; t < CHUNK; t++) {
        const int row = c * CHUNK + t;
        float dtraw = bdt_d
            + sRow[t][0] * w0.x + sRow[t][1] * w0.y + sRow[t][2] * w0.z + sRow[t][3] * w0.w
            + sRow[t][4] * w1.x + sRow[t][5] * w1.y + sRow[t][6] * w1.z + sRow[t][7] * w1.w;
        // stable softplus
        float dtv = fmaxf(dtraw, 0.f) + log1pf(__expf(-fabsf(dtraw)));
        float uv = u[(size_t)row * DINNER + d];
        float du = dtv * uv;
        float y = 0.f;
        if constexpr (!PHASEC) sumdt += dtv;
#pragma unroll
        for (int s = 0; s < DSTATE; s++) {
            float a = __expf(dtv * Areg[s]);
            h[s] = h[s] * a + du * sRow[t][8 + s];
            if constexpr (PHASEC) y = fmaf(h[s], sRow[t][24 + s], y);
        }
        if constexpr (PHASEC) {
            float z = xz[(size_t)row * 512 + 256 + d];
            float sil = z / (1.f + __expf(-z));
            yout[(size_t)row * DINNER + d] = (y + uv * Dd) * sil;
        }
    }
    if constexpr (!PHASEC) {
        size_t base = (size_t)c * NCH + (size_t)d * DSTATE;
#pragma unroll
        for (int s = 0; s < DSTATE; s++) {
            h_loc[base + s] = h[s];
            a_prod[base + s] = __expf(Areg[s] * sumdt);
        }
    }
}

// prefix over chunks: h_init[c] = state entering chunk c
__global__ __launch_bounds__(256) void scan_phaseB(
    const float* __restrict__ a_prod, const float* __restrict__ h_loc, float* __restrict__ h_init)
{
    int ch = blockIdx.x * 256 + threadIdx.x;
    float h = 0.f;
#pragma unroll 8
    for (int c = 0; c < NCHUNK; c++) {
        h_init[(size_t)c * NCH + ch] = h;
        h = fmaf(h, a_prod[(size_t)c * NCH + ch], h_loc[(size_t)c * NCH + ch]);
    }
}

__global__ __launch_bounds__(256) void attn2_kernel(
    const float* __restrict__ Atmp, const float* __restrict__ w2, const float* __restrict__ b2,
    float* __restrict__ araw)
{
    int t = blockIdx.x * 256 + threadIdx.x;
    float acc = b2[0];
#pragma unroll
    for (int a4 = 0; a4 < ATTNDIM / 4; a4++) {
        float4 av = *reinterpret_cast<const float4*>(&Atmp[(size_t)t * ATTNDIM + a4 * 4]);
        float4 wv = *reinterpret_cast<const float4*>(&w2[a4 * 4]);
        acc += av.x * wv.x + av.y * wv.y + av.z * wv.z + av.w * wv.w;
    }
    araw[t] = acc;
}

// single block: softmax max & denom over 16384; also zeroes pooled accumulator
__global__ __launch_bounds__(1024) void softmax_reduce_kernel(
    const float* __restrict__ araw, float* __restrict__ small)
{
    __shared__ float red[16];
    __shared__ float sM;
    int tid = threadIdx.x;
    float m = -1e30f;
    for (int i = tid; i < LSEQ; i += 1024) m = fmaxf(m, araw[i]);
#pragma unroll
    for (int o = 1; o < 64; o <<= 1) m = fmaxf(m, __shfl_xor(m, o));
    if ((tid & 63) == 0) red[tid >> 6] = m;
    __syncthreads();
    if (tid == 0) {
        float mm = red[0];
        for (int i = 1; i < 16; i++) mm = fmaxf(mm, red[i]);
        sM = mm;
    }
    __syncthreads();
    float M = sM;
    float s = 0.f;
    for (int i = tid; i < LSEQ; i += 1024) s += __expf(araw[i] - M);
#pragma unroll
    for (int o = 1; o < 64; o <<= 1) s += __shfl_xor(s, o);
    if ((tid & 63) == 0) red[tid >> 6] = s;
    __syncthreads();
    if (tid == 0) {
        float ss = 0.f;
        for (int i = 0; i < 16; i++) ss += red[i];
        small[0] = M;
        small[1] = ss;
    }
    if (tid < DMODEL) small[16 + tid] = 0.f;
}

__global__ __launch_bounds__(128) void pooled_kernel(
    const float* __restrict__ araw, const float* __restrict__ hn2,
    const float* __restrict__ small, float* __restrict__ pooled)
{
    __shared__ float wsh[128];
    int b = blockIdx.x;
    int n = threadIdx.x;
    float M = small[0];
    float Sinv = 1.f / small[1];
    int t0 = b * 128;
    wsh[n] = __expf(araw[t0 + n] - M) * Sinv;
    __syncthreads();
    float acc = 0.f;
    for (int tt = 0; tt < 128; tt++)
        acc = fmaf(wsh[tt], hn2[(size_t)(t0 + tt) * DMODEL + n], acc);
    atomicAdd(&pooled[n], acc);
}

__global__ void final_kernel(const float* __restrict__ pooled, const float* __restrict__ clf_w,
                             const float* __restrict__ clf_b, float* __restrict__ out)
{
    if (threadIdx.x == 0 && blockIdx.x == 0) {
        float lg[NCLASSES];
        for (int c = 0; c < NCLASSES; c++) {
            float acc = clf_b[c];
            for (int n = 0; n < DMODEL; n++) acc += pooled[n] * clf_w[c * DMODEL + n];
            lg[c] = acc;
        }
        float m = lg[0];
        int am = 0;
        for (int c = 1; c < NCLASSES; c++) if (lg[c] > m) { m = lg[c]; am = c; }
        float e[NCLASSES];
        float s = 0.f;
        for (int c = 0; c < NCLASSES; c++) { e[c] = __expf(lg[c] - m); s += e[c]; }
        for (int c = 0; c < NCLASSES; c++) out[c] = lg[c];
        for (int c = 0; c < NCLASSES; c++) out[4 + c] = e[c] / s;
        out[8] = (float)am;
    }
}

extern "C" void kernel_launch(void* const* d_in, const int* in_sizes, int n_in,
                              void* d_out, int out_size, void* d_ws, size_t ws_size,
                              hipStream_t stream)
{
    const float* x         = (const float*)d_in[0];
    const float* fc1_w     = (const float*)d_in[1];
    const float* fc1_b     = (const float*)d_in[2];
    const float* ln_w      = (const float*)d_in[3];
    const float* ln_b      = (const float*)d_in[4];
    const float* in_proj_w = (const float*)d_in[5];
    const float* conv_w    = (const float*)d_in[6];
    const float* conv_b    = (const float*)d_in[7];
    const float* x_proj_w  = (const float*)d_in[8];
    const float* dt_proj_w = (const float*)d_in[9];
    const float* dt_proj_b = (const float*)d_in[10];
    const float* A_log     = (const float*)d_in[11];
    const float* Dp        = (const float*)d_in[12];
    const float* out_proj_w= (const float*)d_in[13];
    const float* norm_w    = (const float*)d_in[14];
    const float* norm_b    = (const float*)d_in[15];
    const float* attn_w1   = (const float*)d_in[16];
    const float* attn_b1   = (const float*)d_in[17];
    const float* attn_w2   = (const float*)d_in[18];
    const float* attn_b2   = (const float*)d_in[19];
    const float* clf_w     = (const float*)d_in[20];
    const float* clf_b     = (const float*)d_in[21];
    const int*   ratep     = (const int*)d_in[22];

    float* ws     = (float*)d_ws;
    float* B_h    = ws;                                  // L*128
    float* B_tmp  = B_h   + (size_t)LSEQ * DMODEL;       // L*128 (hn_perm / dbl / hn2)
    float* B_xz   = B_tmp + (size_t)LSEQ * DMODEL;       // L*512
    float* B_xs   = B_xz  + (size_t)LSEQ * 512;          // L*256 (u / y / Atmp)
    float* B_ap   = B_xs  + (size_t)LSEQ * DINNER;       // NCHUNK*4096
    float* B_hl   = B_ap  + (size_t)NCHUNK * NCH;
    float* B_hi   = B_hl  + (size_t)NCHUNK * NCH;
    float* B_small= B_hi  + (size_t)NCHUNK * NCH;        // 256
    float* out    = (float*)d_out;
    float* araw   = out + 9;

    // h = relu(x @ fc1_w.T + fc1_b)
    gemm_tn<64,128,32,4,8,1,0><<<dim3(LSEQ/64, 1), 256, 0, stream>>>(
        x, 1024, fc1_w, fc1_b, B_h, DMODEL, LSEQ, DMODEL, 1024, ratep);

    for (int l = 0; l < NLAYERS; l++) {
        // hn_perm = LN(h)[perm]
        ln_kernel<true><<<LSEQ/4, 256, 0, stream>>>(
            B_h, ln_w + l*DMODEL, ln_b + l*DMODEL, B_tmp, ratep);
        // xz = hn_perm @ in_proj_w.T
        gemm_tn<64,128,32,4,8,0,0><<<dim3(LSEQ/64, 4), 256, 0, stream>>>(
            B_tmp, DMODEL, in_proj_w + (size_t)l*512*DMODEL, nullptr, B_xz, 512,
            LSEQ, 512, DMODEL, ratep);
        // u = silu(causal_conv4(x))
        conv_silu_kernel<<<(LSEQ*DINNER)/256, 256, 0, stream>>>(
            B_xz, conv_w + l*DINNER*DCONV, conv_b + l*DINNER, B_xs);
        // dbl = u @ x_proj_w.T  (into B_tmp; hn_perm dead)
        gemm_tn<64,64,32,4,4,0,0><<<dim3(LSEQ/64, 1), 256, 0, stream>>>(
            B_xs, DINNER, x_proj_w + (size_t)l*(DTRANK+2*DSTATE)*DINNER, nullptr, B_tmp, 40,
            LSEQ, DTRANK + 2*DSTATE, DINNER, ratep);
        // chunked scan
        scan_phase<false><<<NCHUNK, 256, 0, stream>>>(
            B_xs, B_tmp, dt_proj_w + (size_t)l*DINNER*DTRANK, dt_proj_b + l*DINNER,
            A_log + (size_t)l*DINNER*DSTATE, nullptr, nullptr, nullptr,
            B_ap, B_hl, nullptr);
        scan_phaseB<<<NCH/256, 256, 0, stream>>>(B_ap, B_hl, B_hi);
        scan_phase<true><<<NCHUNK, 256, 0, stream>>>(
            B_xs, B_tmp, dt_proj_w + (size_t)l*DINNER*DTRANK, dt_proj_b + l*DINNER,
            A_log + (size_t)l*DINNER*DSTATE, Dp + l*DINNER, B_xz, B_hi,
            nullptr, nullptr, B_xs);
        // h[perm(j)] += y @ out_proj_w.T
        gemm_tn<64,128,32,4,8,0,1><<<dim3(LSEQ/64, 1), 256, 0, stream>>>(
            B_xs, DINNER, out_proj_w + (size_t)l*DMODEL*DINNER, nullptr, B_h, DMODEL,
            LSEQ, DMODEL, DINNER, ratep);
    }

    // hn2 = LN(h)
    ln_kernel<false><<<LSEQ/4, 256, 0, stream>>>(B_h, norm_w, norm_b, B_tmp, ratep);
    // Atmp = tanh(hn2 @ attn_w1.T + attn_b1)
    gemm_tn<64,64,32,4,4,2,0><<<dim3(LSEQ/64, 1), 256, 0, stream>>>(
        B_tmp, DMODEL, attn_w1, attn_b1, B_xs, ATTNDIM, LSEQ, ATTNDIM, DMODEL, ratep);
    // A_raw = Atmp @ attn_w2.T + attn_b2
    attn2_kernel<<<LSEQ/256, 256, 0, stream>>>(B_xs, attn_w2, attn_b2, araw);
    softmax_reduce_kernel<<<1, 1024, 0, stream>>>(araw, B_small);
    pooled_kernel<<<LSEQ/128, 128, 0, stream>>>(araw, B_tmp, B_small, B_small + 16);
    final_kernel<<<1, 64, 0, stream>>>(B_small + 16, clf_w, clf_b, out);
}

// Round 2
// 426.360 us; speedup vs baseline: 1.5840x; 1.5840x over previous
//
#include <hip/hip_runtime.h>
#include <math.h>

#define LSEQ 16384
#define DMODEL 128
#define DINNER 256
#define DSTATE 16
#define DCONV 4
#define DTRANK 8
#define NLAYERS 2
#define ATTNDIM 64
#define NCLASSES 4
#define CHUNK 64
#define NCHUNK (LSEQ / CHUNK)      /* 256 */
#define NCH (DINNER * DSTATE)      /* 4096 */

typedef unsigned short ushort_t;
typedef short bf16x8 __attribute__((ext_vector_type(8)));
typedef float f32x4 __attribute__((ext_vector_type(4)));

__device__ __forceinline__ ushort_t f2bf(float v) {
    unsigned int u = __float_as_uint(v);
    unsigned int r = (u + 0x7FFFu + ((u >> 16) & 1u)) >> 16;
    return (ushort_t)r;
}

// permuted position j -> original index perm[j]
__device__ __forceinline__ int perm_of(int j, int rate) {
    int q = LSEQ / rate;
    int r = LSEQ - q * rate;
    int thresh = r * (q + 1);
    int i, k;
    if (j < thresh) { i = j / (q + 1); k = j - i * (q + 1); }
    else { int j2 = j - thresh; i = r + j2 / q; k = j2 - (i - r) * q; }
    return i + rate * k;
}

// ---------------- weight conversion (f32 -> bf16), all weights fused ------------
// layout in wbf (ushort offsets):
//  fc1   @ 0        size 131072  (128 x 1024)
//  inprj @ 131072   size 131072  (2 x 512 x 128)
//  xprj  @ 262144   size 20480   (2 x 40 x 256)
//  oprj  @ 282624   size 65536   (2 x 128 x 256)
//  attn1 @ 348160   size 8192    (64 x 128)
#define WOFF_FC1   0
#define WOFF_INPRJ 131072
#define WOFF_XPRJ  262144
#define WOFF_OPRJ  282624
#define WOFF_ATTN1 348160
#define WTOTAL     356352

__global__ __launch_bounds__(256) void convert_weights(
    const float* __restrict__ fc1_w, const float* __restrict__ in_proj_w,
    const float* __restrict__ x_proj_w, const float* __restrict__ out_proj_w,
    const float* __restrict__ attn_w1, ushort_t* __restrict__ wbf)
{
    int idx = blockIdx.x * 256 + threadIdx.x;
    if (idx >= WTOTAL) return;
    const float* src; int off;
    if (idx < WOFF_INPRJ)      { src = fc1_w;      off = idx; }
    else if (idx < WOFF_XPRJ)  { src = in_proj_w;  off = idx - WOFF_INPRJ; }
    else if (idx < WOFF_OPRJ)  { src = x_proj_w;   off = idx - WOFF_XPRJ; }
    else if (idx < WOFF_ATTN1) { src = out_proj_w; off = idx - WOFF_OPRJ; }
    else                       { src = attn_w1;    off = idx - WOFF_ATTN1; }
    wbf[idx] = f2bf(src[off]);
}

// ---------------- bf16 MFMA GEMM:  C[M][ldc] = act(A[M][K] @ W[N][K]^T + bias) --
// ACT 0 none, 1 relu, 2 tanh.  MODE 0 store, 1 C[perm(m)][n] += v.
// AF32: A is f32 in global, converted to bf16 during staging.
template<int ACT, int MODE, bool AF32>
__global__ __launch_bounds__(256) void gemm_mfma(
    const void* __restrict__ Aptr, const ushort_t* __restrict__ W,
    const float* __restrict__ bias, float* __restrict__ C, int ldc,
    int N, int K, const int* __restrict__ ratep)
{
    constexpr int BK = 64;
    __shared__ ushort_t sA[64][BK + 8];
    __shared__ ushort_t sB[64][BK + 8];
    const int tid = threadIdx.x;
    const int lane = tid & 63;
    const int wv = tid >> 6;
    const int m0 = blockIdx.x * 64;
    const int n0 = blockIdx.y * 64;
    const float* Af = (const float*)Aptr;
    const ushort_t* Ab = (const ushort_t*)Aptr;

    f32x4 acc[4];
#pragma unroll
    for (int nf = 0; nf < 4; nf++)
#pragma unroll
        for (int r = 0; r < 4; r++) acc[nf][r] = 0.f;

    for (int k0 = 0; k0 < K; k0 += BK) {
#pragma unroll
        for (int it = 0; it < 2; it++) {
            int idx = it * 256 + tid;          // 512 chunks of 8 elements
            int row = idx >> 3, c8 = (idx & 7) * 8;
            bf16x8 v;
            if constexpr (AF32) {
                const float* p = &Af[(size_t)(m0 + row) * K + k0 + c8];
                float4 f0 = *reinterpret_cast<const float4*>(p);
                float4 f1 = *reinterpret_cast<const float4*>(p + 4);
                v[0] = (short)f2bf(f0.x); v[1] = (short)f2bf(f0.y);
                v[2] = (short)f2bf(f0.z); v[3] = (short)f2bf(f0.w);
                v[4] = (short)f2bf(f1.x); v[5] = (short)f2bf(f1.y);
                v[6] = (short)f2bf(f1.z); v[7] = (short)f2bf(f1.w);
            } else {
                v = *reinterpret_cast<const bf16x8*>(&Ab[(size_t)(m0 + row) * K + k0 + c8]);
            }
            *reinterpret_cast<bf16x8*>(&sA[row][c8]) = v;
        }
#pragma unroll
        for (int it = 0; it < 2; it++) {
            int idx = it * 256 + tid;
            int row = idx >> 3, c8 = (idx & 7) * 8;
            bf16x8 v;
            if (n0 + row < N) {
                v = *reinterpret_cast<const bf16x8*>(&W[(size_t)(n0 + row) * K + k0 + c8]);
            } else {
#pragma unroll
                for (int e = 0; e < 8; e++) v[e] = 0;
            }
            *reinterpret_cast<bf16x8*>(&sB[row][c8]) = v;
        }
        __syncthreads();
#pragma unroll
        for (int ks = 0; ks < 2; ks++) {
            int ak = ks * 32 + (lane >> 4) * 8;
            bf16x8 af = *reinterpret_cast<const bf16x8*>(&sA[wv * 16 + (lane & 15)][ak]);
#pragma unroll
            for (int nf = 0; nf < 4; nf++) {
                bf16x8 bfr = *reinterpret_cast<const bf16x8*>(&sB[nf * 16 + (lane & 15)][ak]);
                acc[nf] = __builtin_amdgcn_mfma_f32_16x16x32_bf16(af, bfr, acc[nf], 0, 0, 0);
            }
        }
        __syncthreads();
    }

    int rate = 0;
    if constexpr (MODE == 1) rate = *ratep;
    const int rbase = m0 + wv * 16 + (lane >> 4) * 4;
    const int cbase = n0 + (lane & 15);
#pragma unroll
    for (int nf = 0; nf < 4; nf++) {
        int col = cbase + nf * 16;
        if (col < N) {
            float bv = bias ? bias[col] : 0.f;
#pragma unroll
            for (int r = 0; r < 4; r++) {
                int row = rbase + r;
                float v = acc[nf][r] + bv;
                if constexpr (ACT == 1) v = fmaxf(v, 0.f);
                if constexpr (ACT == 2) v = tanhf(v);
                if constexpr (MODE == 1) {
                    int orow = perm_of(row, rate);
                    C[(size_t)orow * ldc + col] += v;
                } else {
                    C[(size_t)row * ldc + col] = v;
                }
            }
        }
    }
}

// ---------------- layernorm over 128; GATHER: row j reads source row perm(j) ----
// writes bf16 always; optionally f32 too.
template<bool GATHER>
__global__ __launch_bounds__(256) void ln_kernel(
    const float* __restrict__ h, const float* __restrict__ w, const float* __restrict__ b,
    ushort_t* __restrict__ out_bf, float* __restrict__ out_f32, const int* __restrict__ ratep)
{
    int lane = threadIdx.x & 63;
    int rowInBlk = threadIdx.x >> 6;
    int j = blockIdx.x * 4 + rowInBlk;
    int src = j;
    if (GATHER) src = perm_of(j, *ratep);
    float2 v = *reinterpret_cast<const float2*>(&h[(size_t)src * DMODEL + lane * 2]);
    float s = v.x + v.y;
    float s2 = v.x * v.x + v.y * v.y;
#pragma unroll
    for (int o = 1; o < 64; o <<= 1) {
        s += __shfl_xor(s, o);
        s2 += __shfl_xor(s2, o);
    }
    float mean = s * (1.f / DMODEL);
    float var = s2 * (1.f / DMODEL) - mean * mean;
    float inv = rsqrtf(var + 1e-5f);
    float2 wv = *reinterpret_cast<const float2*>(&w[lane * 2]);
    float2 bv = *reinterpret_cast<const float2*>(&b[lane * 2]);
    float2 o2;
    o2.x = (v.x - mean) * inv * wv.x + bv.x;
    o2.y = (v.y - mean) * inv * wv.y + bv.y;
    unsigned int packed = (unsigned int)f2bf(o2.x) | ((unsigned int)f2bf(o2.y) << 16);
    *reinterpret_cast<unsigned int*>(&out_bf[(size_t)j * DMODEL + lane * 2]) = packed;
    if (out_f32)
        *reinterpret_cast<float2*>(&out_f32[(size_t)j * DMODEL + lane * 2]) = o2;
}

// ---------------- depthwise causal conv (k=4) + silu; writes f32 and bf16 -------
__global__ __launch_bounds__(256) void conv_silu_kernel(
    const float* __restrict__ xz, const float* __restrict__ cw, const float* __restrict__ cb,
    float* __restrict__ u, ushort_t* __restrict__ ubf)
{
    int idx = blockIdx.x * 256 + threadIdx.x;
    int d = idx & (DINNER - 1);
    int j = idx >> 8;
    float4 wv = *reinterpret_cast<const float4*>(&cw[d * 4]);
    const float* wp = reinterpret_cast<const float*>(&wv);
    float acc = cb[d];
#pragma unroll
    for (int k = 0; k < DCONV; k++) {
        int t = j - (DCONV - 1) + k;
        if (t >= 0) acc += xz[(size_t)t * 512 + d] * wp[k];
    }
    float sig = 1.f / (1.f + __expf(-acc));
    float val = acc * sig;
    u[idx] = val;
    ubf[idx] = f2bf(val);
}

// ---------------- chunked selective scan --------------------------------------
template<bool PHASEC>
__global__ __launch_bounds__(256) void scan_phase(
    const float* __restrict__ u, const float* __restrict__ dbl,
    const float* __restrict__ Wdt, const float* __restrict__ bdt,
    const float* __restrict__ A_log,
    const float* __restrict__ Dp, const float* __restrict__ xz,
    const float* __restrict__ h_init,
    float* __restrict__ a_prod, float* __restrict__ h_loc,
    ushort_t* __restrict__ ybf)
{
    __shared__ float sRow[CHUNK][40];
    const int c = blockIdx.x;
    const int tid = threadIdx.x;
    for (int idx4 = tid; idx4 < CHUNK * 10; idx4 += 256) {
        int t = idx4 / 10;
        int c4 = idx4 % 10;
        float4 v = *reinterpret_cast<const float4*>(&dbl[(size_t)(c * CHUNK + t) * 40 + c4 * 4]);
        sRow[t][c4 * 4 + 0] = v.x; sRow[t][c4 * 4 + 1] = v.y;
        sRow[t][c4 * 4 + 2] = v.z; sRow[t][c4 * 4 + 3] = v.w;
    }
    __syncthreads();
    const int d = tid;
    float Areg[DSTATE];
#pragma unroll
    for (int s4 = 0; s4 < 4; s4++) {
        float4 v = *reinterpret_cast<const float4*>(&A_log[(size_t)d * DSTATE + s4 * 4]);
        Areg[s4 * 4 + 0] = -expf(v.x); Areg[s4 * 4 + 1] = -expf(v.y);
        Areg[s4 * 4 + 2] = -expf(v.z); Areg[s4 * 4 + 3] = -expf(v.w);
    }
    float4 w0 = *reinterpret_cast<const float4*>(&Wdt[(size_t)d * 8]);
    float4 w1 = *reinterpret_cast<const float4*>(&Wdt[(size_t)d * 8 + 4]);
    const float bdt_d = bdt[d];
    float h[DSTATE];
    if constexpr (PHASEC) {
        size_t base = (size_t)c * NCH + (size_t)d * DSTATE;
#pragma unroll
        for (int s4 = 0; s4 < 4; s4++) {
            float4 v = *reinterpret_cast<const float4*>(&h_init[base + s4 * 4]);
            h[s4 * 4 + 0] = v.x; h[s4 * 4 + 1] = v.y;
            h[s4 * 4 + 2] = v.z; h[s4 * 4 + 3] = v.w;
        }
    } else {
#pragma unroll
        for (int s = 0; s < DSTATE; s++) h[s] = 0.f;
    }
    float Dd = 0.f;
    if constexpr (PHASEC) Dd = Dp[d];
    float sumdt = 0.f;
    for (int t = 0; t < CHUNK; t++) {
        const int row = c * CHUNK + t;
        float dtraw = bdt_d
            + sRow[t][0] * w0.x + sRow[t][1] * w0.y + sRow[t][2] * w0.z + sRow[t][3] * w0.w
            + sRow[t][4] * w1.x + sRow[t][5] * w1.y + sRow[t][6] * w1.z + sRow[t][7] * w1.w;
        float dtv = fmaxf(dtraw, 0.f) + log1pf(__expf(-fabsf(dtraw)));
        float uv = u[(size_t)row * DINNER + d];
        float du = dtv * uv;
        float y = 0.f;
        if constexpr (!PHASEC) sumdt += dtv;
#pragma unroll
        for (int s = 0; s < DSTATE; s++) {
            float a = __expf(dtv * Areg[s]);
            h[s] = h[s] * a + du * sRow[t][8 + s];
            if constexpr (PHASEC) y = fmaf(h[s], sRow[t][24 + s], y);
        }
        if constexpr (PHASEC) {
            float z = xz[(size_t)row * 512 + 256 + d];
            float sil = z / (1.f + __expf(-z));
            ybf[(size_t)row * DINNER + d] = f2bf((y + uv * Dd) * sil);
        }
    }
    if constexpr (!PHASEC) {
        size_t base = (size_t)c * NCH + (size_t)d * DSTATE;
#pragma unroll
        for (int s = 0; s < DSTATE; s++) {
            h_loc[base + s] = h[s];
            a_prod[base + s] = __expf(Areg[s] * sumdt);
        }
    }
}

// prefix over chunks: h_init[c] = state entering chunk c
__global__ __launch_bounds__(256) void scan_phaseB(
    const float* __restrict__ a_prod, const float* __restrict__ h_loc, float* __restrict__ h_init)
{
    int ch = blockIdx.x * 256 + threadIdx.x;
    float h = 0.f;
#pragma unroll 8
    for (int c = 0; c < NCHUNK; c++) {
        h_init[(size_t)c * NCH + ch] = h;
        h = fmaf(h, a_prod[(size_t)c * NCH + ch], h_loc[(size_t)c * NCH + ch]);
    }
}

__global__ __launch_bounds__(256) void attn2_kernel(
    const float* __restrict__ Atmp, const float* __restrict__ w2, const float* __restrict__ b2,
    float* __restrict__ araw)
{
    int t = blockIdx.x * 256 + threadIdx.x;
    float acc = b2[0];
#pragma unroll
    for (int a4 = 0; a4 < ATTNDIM / 4; a4++) {
        float4 av = *reinterpret_cast<const float4*>(&Atmp[(size_t)t * ATTNDIM + a4 * 4]);
        float4 wv = *reinterpret_cast<const float4*>(&w2[a4 * 4]);
        acc += av.x * wv.x + av.y * wv.y + av.z * wv.z + av.w * wv.w;
    }
    araw[t] = acc;
}

__global__ __launch_bounds__(1024) void softmax_reduce_kernel(
    const float* __restrict__ araw, float* __restrict__ small)
{
    __shared__ float red[16];
    __shared__ float sM;
    int tid = threadIdx.x;
    float m = -1e30f;
    for (int i = tid; i < LSEQ; i += 1024) m = fmaxf(m, araw[i]);
#pragma unroll
    for (int o = 1; o < 64; o <<= 1) m = fmaxf(m, __shfl_xor(m, o));
    if ((tid & 63) == 0) red[tid >> 6] = m;
    __syncthreads();
    if (tid == 0) {
        float mm = red[0];
        for (int i = 1; i < 16; i++) mm = fmaxf(mm, red[i]);
        sM = mm;
    }
    __syncthreads();
    float M = sM;
    float s = 0.f;
    for (int i = tid; i < LSEQ; i += 1024) s += __expf(araw[i] - M);
#pragma unroll
    for (int o = 1; o < 64; o <<= 1) s += __shfl_xor(s, o);
    if ((tid & 63) == 0) red[tid >> 6] = s;
    __syncthreads();
    if (tid == 0) {
        float ss = 0.f;
        for (int i = 0; i < 16; i++) ss += red[i];
        small[0] = M;
        small[1] = ss;
    }
    if (tid < DMODEL) small[16 + tid] = 0.f;
}

__global__ __launch_bounds__(128) void pooled_kernel(
    const float* __restrict__ araw, const float* __restrict__ hn2,
    const float* __restrict__ small, float* __restrict__ pooled)
{
    __shared__ float wsh[128];
    int b = blockIdx.x;
    int n = threadIdx.x;
    float M = small[0];
    float Sinv = 1.f / small[1];
    int t0 = b * 128;
    wsh[n] = __expf(araw[t0 + n] - M) * Sinv;
    __syncthreads();
    float acc = 0.f;
    for (int tt = 0; tt < 128; tt++)
        acc = fmaf(wsh[tt], hn2[(size_t)(t0 + tt) * DMODEL + n], acc);
    atomicAdd(&pooled[n], acc);
}

__global__ void final_kernel(const float* __restrict__ pooled, const float* __restrict__ clf_w,
                             const float* __restrict__ clf_b, float* __restrict__ out)
{
    if (threadIdx.x == 0 && blockIdx.x == 0) {
        float lg[NCLASSES];
        for (int c = 0; c < NCLASSES; c++) {
            float acc = clf_b[c];
            for (int n = 0; n < DMODEL; n++) acc += pooled[n] * clf_w[c * DMODEL + n];
            lg[c] = acc;
        }
        float m = lg[0];
        int am = 0;
        for (int c = 1; c < NCLASSES; c++) if (lg[c] > m) { m = lg[c]; am = c; }
        float e[NCLASSES];
        float s = 0.f;
        for (int c = 0; c < NCLASSES; c++) { e[c] = __expf(lg[c] - m); s += e[c]; }
        for (int c = 0; c < NCLASSES; c++) out[c] = lg[c];
        for (int c = 0; c < NCLASSES; c++) out[4 + c] = e[c] / s;
        out[8] = (float)am;
    }
}

extern "C" void kernel_launch(void* const* d_in, const int* in_sizes, int n_in,
                              void* d_out, int out_size, void* d_ws, size_t ws_size,
                              hipStream_t stream)
{
    const float* x         = (const float*)d_in[0];
    const float* fc1_w     = (const float*)d_in[1];
    const float* fc1_b     = (const float*)d_in[2];
    const float* ln_w      = (const float*)d_in[3];
    const float* ln_b      = (const float*)d_in[4];
    const float* in_proj_w = (const float*)d_in[5];
    const float* conv_w    = (const float*)d_in[6];
    const float* conv_b    = (const float*)d_in[7];
    const float* x_proj_w  = (const float*)d_in[8];
    const float* dt_proj_w = (const float*)d_in[9];
    const float* dt_proj_b = (const float*)d_in[10];
    const float* A_log     = (const float*)d_in[11];
    const float* Dp        = (const float*)d_in[12];
    const float* out_proj_w= (const float*)d_in[13];
    const float* norm_w    = (const float*)d_in[14];
    const float* norm_b    = (const float*)d_in[15];
    const float* attn_w1   = (const float*)d_in[16];
    const float* attn_b1   = (const float*)d_in[17];
    const float* attn_w2   = (const float*)d_in[18];
    const float* attn_b2   = (const float*)d_in[19];
    const float* clf_w     = (const float*)d_in[20];
    const float* clf_b     = (const float*)d_in[21];
    const int*   ratep     = (const int*)d_in[22];

    float* ws     = (float*)d_ws;
    float* B_h    = ws;                                  // L*128 f32
    float* B_tmp  = B_h   + (size_t)LSEQ * DMODEL;       // L*128 f32 (dbl / hn2)
    float* B_xz   = B_tmp + (size_t)LSEQ * DMODEL;       // L*512 f32
    float* B_u    = B_xz  + (size_t)LSEQ * 512;          // L*256 f32 (u / Atmp)
    float* B_ap   = B_u   + (size_t)LSEQ * DINNER;       // NCHUNK*NCH
    float* B_hl   = B_ap  + (size_t)NCHUNK * NCH;        // NCHUNK*NCH
    float* B_hi   = B_hl  + (size_t)NCHUNK * NCH;        // NCHUNK*NCH
    float* B_small= B_hi  + (size_t)NCHUNK * NCH;        // 256
    ushort_t* wbf = (ushort_t*)(B_small + 256);          // WTOTAL ushorts
    // bf16 aliases (lifetimes disjoint with aliased f32 buffers):
    ushort_t* hnbf = (ushort_t*)B_hi;                    // L*128 bf16 == 4MB == B_hi
    ushort_t* uybf = (ushort_t*)B_ap;                    // L*256 bf16 == 8MB == B_ap+B_hl
    float* out    = (float*)d_out;
    float* araw   = out + 9;

    convert_weights<<<(WTOTAL + 255) / 256, 256, 0, stream>>>(
        fc1_w, in_proj_w, x_proj_w, out_proj_w, attn_w1, wbf);

    // h = relu(x @ fc1_w.T + fc1_b)
    gemm_mfma<1, 0, true><<<dim3(LSEQ / 64, 2), 256, 0, stream>>>(
        x, wbf + WOFF_FC1, fc1_b, B_h, DMODEL, DMODEL, 1024, ratep);

    for (int l = 0; l < NLAYERS; l++) {
        // hn_perm (bf16) = LN(h)[perm]
        ln_kernel<true><<<LSEQ / 4, 256, 0, stream>>>(
            B_h, ln_w + l * DMODEL, ln_b + l * DMODEL, hnbf, nullptr, ratep);
        // xz = hn_perm @ in_proj_w.T  (f32 out)
        gemm_mfma<0, 0, false><<<dim3(LSEQ / 64, 8), 256, 0, stream>>>(
            hnbf, wbf + WOFF_INPRJ + l * 65536, nullptr, B_xz, 512, 512, DMODEL, ratep);
        // u = silu(causal_conv4(x));  f32 + bf16
        conv_silu_kernel<<<(LSEQ * DINNER) / 256, 256, 0, stream>>>(
            B_xz, conv_w + l * DINNER * DCONV, conv_b + l * DINNER, B_u, uybf);
        // dbl = u @ x_proj_w.T   (f32 out, ldc=40)
        gemm_mfma<0, 0, false><<<dim3(LSEQ / 64, 1), 256, 0, stream>>>(
            uybf, wbf + WOFF_XPRJ + l * 10240, nullptr, B_tmp, 40,
            DTRANK + 2 * DSTATE, DINNER, ratep);
        // chunked scan (uybf dead from here; B_ap/B_hl reused)
        scan_phase<false><<<NCHUNK, 256, 0, stream>>>(
            B_u, B_tmp, dt_proj_w + (size_t)l * DINNER * DTRANK, dt_proj_b + l * DINNER,
            A_log + (size_t)l * DINNER * DSTATE, nullptr, nullptr, nullptr,
            B_ap, B_hl, nullptr);
        scan_phaseB<<<NCH / 256, 256, 0, stream>>>(B_ap, B_hl, B_hi);
        scan_phase<true><<<NCHUNK, 256, 0, stream>>>(
            B_u, B_tmp, dt_proj_w + (size_t)l * DINNER * DTRANK, dt_proj_b + l * DINNER,
            A_log + (size_t)l * DINNER * DSTATE, Dp + l * DINNER, B_xz, B_hi,
            nullptr, nullptr, uybf);
        // h[perm(j)] += y @ out_proj_w.T
        gemm_mfma<0, 1, false><<<dim3(LSEQ / 64, 2), 256, 0, stream>>>(
            uybf, wbf + WOFF_OPRJ + l * 32768, nullptr, B_h, DMODEL, DMODEL, DINNER, ratep);
    }

    // hn2 = LN(h): bf16 for attn1, f32 for pooling
    ln_kernel<false><<<LSEQ / 4, 256, 0, stream>>>(B_h, norm_w, norm_b, hnbf, B_tmp, ratep);
    // Atmp = tanh(hn2 @ attn_w1.T + attn_b1)  (f32 out into B_u)
    gemm_mfma<2, 0, false><<<dim3(LSEQ / 64, 1), 256, 0, stream>>>(
        hnbf, wbf + WOFF_ATTN1, attn_b1, B_u, ATTNDIM, ATTNDIM, DMODEL, ratep);
    // A_raw = Atmp @ attn_w2.T + attn_b2
    attn2_kernel<<<LSEQ / 256, 256, 0, stream>>>(B_u, attn_w2, attn_b2, araw);
    softmax_reduce_kernel<<<1, 1024, 0, stream>>>(araw, B_small);
    pooled_kernel<<<LSEQ / 128, 128, 0, stream>>>(araw, B_tmp, B_small, B_small + 16);
    final_kernel<<<1, 64, 0, stream>>>(B_small + 16, clf_w, clf_b, out);
}